// Round 8
// baseline (676.294 us; speedup 1.0000x reference)
//
#include <hip/hip_runtime.h>

#define B_   32
#define N_   64
#define NH   16
#define R_   1024
#define REP  1024
#define M_   1008           // 16*63
#define BM   (B_ * M_)      // 32256
#define NCLS 117

#define MD_DIRECT 0
#define MD_CC1    2   // k<1024: enc[b*64+x]; k>=1024: msgh[row]      (512 rows)

typedef short bhalf8 __attribute__((ext_vector_type(8)));   // 8 bf16 (4 VGPRs)
typedef float f32x4  __attribute__((ext_vector_type(4)));   // MFMA acc

typedef __attribute__((address_space(3))) void       lds_t;
typedef const __attribute__((address_space(1))) void gbl_t;
__device__ __forceinline__ void gld16(const void* g, void* l)
{
    __builtin_amdgcn_global_load_lds((gbl_t*)g, (lds_t*)l, 16, 0, 0);
}

// bijective XCD swizzle (grid = 8q): XCD k gets contiguous wgid [k*q,(k+1)*q)
__device__ __forceinline__ int xcd_swz(int orig, int q)
{
    return (orig & 7) * q + (orig >> 3);
}

__device__ __forceinline__ unsigned short f2bf(float f)
{
    union { float f; unsigned int u; } x; x.f = f;
    unsigned int r = x.u + 0x7FFFu + ((x.u >> 16) & 1u);    // round-nearest-even
    return (unsigned short)(r >> 16);
}
__device__ __forceinline__ float bf2f(unsigned short u)
{
    union { unsigned int i; float f; } x; x.i = ((unsigned int)u) << 16; return x.f;
}

// packed add+relu+pack via v_cvt_pk_bf16_f32
__device__ __forceinline__ unsigned int addrelu2(unsigned int a, unsigned int b)
{
    union { unsigned int u; float f; } la, ha, lb, hb;
    la.u = a << 16;          ha.u = a & 0xffff0000u;
    lb.u = b << 16;          hb.u = b & 0xffff0000u;
    float lo = fmaxf(la.f + lb.f, 0.f);
    float hi = fmaxf(ha.f + hb.f, 0.f);
    unsigned int r;
    asm("v_cvt_pk_bf16_f32 %0, %1, %2" : "=v"(r) : "v"(lo), "v"(hi));
    return r;
}

// counted waits (immediates must be literals -> uniform branch ladder)
__device__ __forceinline__ void wait_vm(int n)
{
    if (n >= 8)      asm volatile("s_waitcnt vmcnt(8)" ::: "memory");
    else if (n == 6) asm volatile("s_waitcnt vmcnt(6)" ::: "memory");
    else if (n == 4) asm volatile("s_waitcnt vmcnt(4)" ::: "memory");
    else if (n == 3) asm volatile("s_waitcnt vmcnt(3)" ::: "memory");
    else if (n == 2) asm volatile("s_waitcnt vmcnt(2)" ::: "memory");
    else             asm volatile("s_waitcnt vmcnt(0)" ::: "memory");
}

// ---------------------------------------------------------------------------
// One-dispatch weight prep + bf16 input convert.
// ---------------------------------------------------------------------------
__device__ __forceinline__ void tr32(const float* in, unsigned short* out,
                                     int K, int N, int local)
{
    __shared__ float t[32][33];
    int kb = K >> 5;
    int k0 = (local % kb) * 32, n0 = (local / kb) * 32;
    int tx = threadIdx.x & 31, ty = threadIdx.x >> 5;
#pragma unroll
    for (int r = 0; r < 4; ++r)
        t[ty + r * 8][tx] = in[(size_t)(k0 + ty + r * 8) * N + n0 + tx];
    __syncthreads();
    // packed u32 writes (2 bf16/store, 4x fewer store instrs): 512 u32, 2/thread
    unsigned int* o32 = (unsigned int*)(out + (size_t)n0 * K + k0);
#pragma unroll
    for (int w = 0; w < 2; ++w) {
        int u = threadIdx.x * 2 + w;            // 0..511
        int n = u >> 4, c = (u & 15) * 2;
        unsigned int val = (unsigned)f2bf(t[c][n]) | ((unsigned)f2bf(t[c + 1][n]) << 16);
        o32[(size_t)n * (K >> 1) + (u & 15)] = val;
    }
}

__global__ __launch_bounds__(256)
void prep_all(const float* __restrict__ W1, const float* __restrict__ W2,
              const float* __restrict__ Wo, const float* __restrict__ Ws,
              const float* __restrict__ Wsu, const float* __restrict__ Wou,
              const float* __restrict__ bo_, const float* __restrict__ b1_,
              const float* __restrict__ feat,
              unsigned short* __restrict__ Wfused, unsigned short* __restrict__ W2t,
              unsigned short* __restrict__ Wst, unsigned short* __restrict__ Wsut,
              unsigned short* __restrict__ Wout, float* __restrict__ biasFull,
              unsigned short* __restrict__ enc0bf)
{
    int bx = blockIdx.x;
    if      (bx < 1024) tr32(W1 + 1024 * 1024, Wfused,               1024, 1024, bx);
    else if (bx < 2048) tr32(Wo,               Wfused + 1024 * 1024, 1024, 1024, bx - 1024);
    else if (bx < 3072) tr32(W1,               Wfused + 2048 * 1024, 1024, 1024, bx - 2048);
    else if (bx < 3584) tr32(W2,  W2t,  1024, 512,  bx - 3072);
    else if (bx < 4608) tr32(Ws,  Wst,  1024, 1024, bx - 3584);
    else if (bx < 6656) tr32(Wsu, Wsut, 2048, 1024, bx - 4608);
    else if (bx < 8704) tr32(Wou, Wout, 2048, 1024, bx - 6656);
    else if (bx < 8716) {
        int c = (bx - 8704) * 256 + threadIdx.x;   // 0..3071
        float v = 0.f;
        if (c >= 2048)      v = b1_[c - 2048];
        else if (c >= 1024) v = bo_[c - 1024];
        biasFull[c] = v;
    } else {
        int i = (bx - 8716) * 256 + threadIdx.x;   // over 2M/8 = 256K
        float4 a = ((const float4*)feat)[2 * i];
        float4 b = ((const float4*)feat)[2 * i + 1];
        uint4 o;
        o.x = (unsigned)f2bf(a.x) | ((unsigned)f2bf(a.y) << 16);
        o.y = (unsigned)f2bf(a.z) | ((unsigned)f2bf(a.w) << 16);
        o.z = (unsigned)f2bf(b.x) | ((unsigned)f2bf(b.y) << 16);
        o.w = (unsigned)f2bf(b.z) | ((unsigned)f2bf(b.w) << 16);
        ((uint4*)enc0bf)[i] = o;
    }
}

// ---------------------------------------------------------------------------
// Fused U/V/Go GEMM.  Two sections in one dispatch (grid 288 = 8*36):
//  wgid < 256 : V|Go  — XX[:, 0..2047]  = enc(all 2048 rows) @ Wf[0..2047]^T
//  wgid >=256 : U     — XX[human rows, 2048..3071] only.
// 128x128 tile, BK=32, block 256.
// ---------------------------------------------------------------------------
__global__ __launch_bounds__(256)
void gemm_uvgo(const unsigned short* __restrict__ enc,
               const unsigned short* __restrict__ Wf,
               const float* __restrict__ biasFull, unsigned short* __restrict__ XX)
{
    __shared__ unsigned short As[3][128 * 32];
    __shared__ unsigned short Bs[3][128 * 32];
    const int tid  = threadIdx.x;
    const int lane = tid & 63, wave = tid >> 6;
    const int wm = wave & 1, wn = wave >> 1;
    const int l15 = lane & 15, lk = lane >> 4;
    const int wgid = xcd_swz(blockIdx.x, 36);           // 288 = 8*36
    const int uSec = wgid >= 256;
    int row0, col0;
    if (!uSec) { row0 = (wgid & 15) * 128;       col0 = (wgid >> 4) * 128; }
    else       { int idx = wgid - 256;
                 row0 = (idx & 3) * 128;         col0 = 2048 + (idx >> 2) * 128; }
    const int kq = (lane & 3) * 8;

    const unsigned short* pA[2];
    const unsigned short* pB[2];
    int ldsOff[2];
#pragma unroll
    for (int i = 0; i < 2; ++i) {
        int tr = wave * 32 + (lane >> 2) + i * 16;
        int grow;
        if (!uSec) grow = row0 + tr;
        else { int hr = row0 + tr; grow = (hr >> 4) * 64 + (hr & 15); }
        pA[i]  = enc + (size_t)grow * 1024 + kq;
        pB[i]  = Wf  + (size_t)(col0 + tr) * 1024 + kq;
        ldsOff[i] = wave * 1024 + i * 512 + lane * 8;
    }

#define STG_UV(slot, k0) do {                          \
        gld16(pA[0] + (k0), &As[slot][ldsOff[0]]);     \
        gld16(pA[1] + (k0), &As[slot][ldsOff[1]]);     \
        gld16(pB[0] + (k0), &Bs[slot][ldsOff[0]]);     \
        gld16(pB[1] + (k0), &Bs[slot][ldsOff[1]]); } while (0)

    f32x4 acc[4][4];
#pragma unroll
    for (int i = 0; i < 4; ++i)
#pragma unroll
    for (int j = 0; j < 4; ++j) acc[i][j] = (f32x4)0.f;

    STG_UV(0, 0);
    STG_UV(1, 32);
    for (int t = 0; t < 32; ++t) {
        const int slot = t % 3;
        if (t + 2 < 32) STG_UV((t + 2) % 3, (t + 2) * 32);
        wait_vm(t < 30 ? 8 : (t == 30 ? 4 : 0));
        __builtin_amdgcn_s_barrier();
        __builtin_amdgcn_sched_barrier(0);
        bhalf8 af[4], bf4[4];
#pragma unroll
        for (int mt = 0; mt < 4; ++mt)
            af[mt] = *(bhalf8*)&As[slot][(wm * 64 + mt * 16 + l15) * 32 + lk * 8];
#pragma unroll
        for (int nt = 0; nt < 4; ++nt)
            bf4[nt] = *(bhalf8*)&Bs[slot][(wn * 64 + nt * 16 + l15) * 32 + lk * 8];
#pragma unroll
        for (int mt = 0; mt < 4; ++mt)
#pragma unroll
        for (int nt = 0; nt < 4; ++nt)
            acc[mt][nt] = __builtin_amdgcn_mfma_f32_16x16x32_bf16(af[mt], bf4[nt],
                                                                  acc[mt][nt], 0, 0, 0);
        __builtin_amdgcn_sched_barrier(0);
        __builtin_amdgcn_s_barrier();
    }
#undef STG_UV

#pragma unroll
    for (int mt = 0; mt < 4; ++mt)
#pragma unroll
    for (int r = 0; r < 4; ++r) {
        int lrow = row0 + wm * 64 + mt * 16 + lk * 4 + r;
        int row = uSec ? ((lrow >> 4) * 64 + (lrow & 15)) : lrow;
#pragma unroll
        for (int nt = 0; nt < 4; ++nt) {
            int col = col0 + wn * 64 + nt * 16 + l15;
            float v = acc[mt][nt][r] + biasFull[col];
            if ((col >> 10) == 1) v = fmaxf(v, 0.f);    // Go region
            XX[(size_t)row * 3072 + col] = f2bf(v);
        }
    }
}

// ---------------------------------------------------------------------------
// One-pass fused pair MLP, TLP variant: 1008 blocks (8*126) x 64 rows x 256
// cols, 512 threads / 8 waves (2 row x 4 col, per-wave 32x64, acc[2][4]).
// LDS 53 KB + VGPR<=128 (__launch_bounds__(512,4)) -> 2-3 blocks/CU so
// independent barrier groups overlap (m114 mechanism): one block computes
// while another waits out its staging drain.  Simple 2-barrier loop, 3-slot
// Bs, reg-prefetched U/V (8B/thread).  Ledger per iter: R(t+1)=2 + S(t+2)=2;
// steady wait vmcnt(6) lgkmcnt(0) (S(t) drained transitively by the auto-wait
// on cu/cv, which are ordered after S(t)); t=31 drains to 0.
// wpart: 2 col-partials (consumers sum both).
// ---------------------------------------------------------------------------
__global__ __launch_bounds__(512, 4)
void pair_bf(const unsigned short* __restrict__ XX,
             const unsigned short* __restrict__ W2t, const float* __restrict__ b2,
             const float* __restrict__ W3f, float* __restrict__ wpart)
{
    __shared__ unsigned short As[64 * 32];              // 4 KB
    __shared__ unsigned short Bs[3][256 * 32];          // 48 KB
    __shared__ float red[4][64];
    const int tid  = threadIdx.x;
    const int lane = tid & 63, wave = tid >> 6;
    const int wr = wave & 1, wc = wave >> 1;            // 2 x 4
    const int l15 = lane & 15, lk = lane >> 4;
    const int wgid = xcd_swz(blockIdx.x, 126);          // 1008 = 8*126
    const int cx = wgid & 1, ry = wgid >> 1;
    const int row0 = ry * 64, col0 = cx * 256;

    // A-staging: 8 threads per row, 8B each
    const int srow = tid >> 3, skq = (tid & 7) * 4;
    int rg = row0 + srow;
    int b  = rg / M_, m = rg % M_;
    int x  = m / 63, jj = m % 63;
    int y  = jj + (jj >= x ? 1 : 0);
    const unsigned short* Up = XX + ((size_t)(b * 64 + x)) * 3072 + 2048 + skq;
    const unsigned short* Vp = XX + ((size_t)(b * 64 + y)) * 3072 + skq;
    const int aw = srow * 32 + skq;

    // B-staging: 2 gld16/thread/step cover [256 cols][32 k]
    const int kq = (lane & 3) * 8;
    const unsigned short* pB[2];
    int bO[2];
#pragma unroll
    for (int i = 0; i < 2; ++i) {
        int trB = i * 128 + (tid >> 2);                 // 0..255
        pB[i] = W2t + (size_t)(col0 + trB) * REP + kq;
        bO[i] = i * 4096 + wave * 512 + lane * 8;       // = trB*32 + (tid&3)*8
    }

#define STG_B(slot, k0) do {                        \
        gld16(pB[0] + (k0), &Bs[slot][bO[0]]);      \
        gld16(pB[1] + (k0), &Bs[slot][bO[1]]); } while (0)

    f32x4 acc[2][4];
#pragma unroll
    for (int i = 0; i < 2; ++i)
#pragma unroll
    for (int j = 0; j < 4; ++j) acc[i][j] = (f32x4)0.f;

    uint2 cu = *(const uint2*)(Up);
    uint2 cv = *(const uint2*)(Vp);
    STG_B(0, 0);
    STG_B(1, 32);

    for (int t = 0; t < 32; ++t) {
        const int slot = t % 3;
        const int kn = (t + 1 < 32) ? (t + 1) * 32 : 0;     // dummy reload at tail
        uint2 nu = *(const uint2*)(Up + kn);
        uint2 nv = *(const uint2*)(Vp + kn);
        if (t + 2 < 32) STG_B((t + 2) % 3, (t + 2) * 32);

        uint2 h;
        h.x = addrelu2(cu.x, cv.x);
        h.y = addrelu2(cu.y, cv.y);
        *(uint2*)&As[aw] = h;

        if (t < 31) asm volatile("s_waitcnt vmcnt(6) lgkmcnt(0)" ::: "memory");
        else        asm volatile("s_waitcnt vmcnt(0) lgkmcnt(0)" ::: "memory");
        __builtin_amdgcn_s_barrier();
        __builtin_amdgcn_sched_barrier(0);
        bhalf8 af[2], bf4[4];
#pragma unroll
        for (int mt = 0; mt < 2; ++mt)
            af[mt] = *(bhalf8*)&As[(wr * 32 + mt * 16 + l15) * 32 + lk * 8];
#pragma unroll
        for (int nt = 0; nt < 4; ++nt)
            bf4[nt] = *(bhalf8*)&Bs[slot][(wc * 64 + nt * 16 + l15) * 32 + lk * 8];
#pragma unroll
        for (int mt = 0; mt < 2; ++mt)
#pragma unroll
        for (int nt = 0; nt < 4; ++nt)
            acc[mt][nt] = __builtin_amdgcn_mfma_f32_16x16x32_bf16(af[mt], bf4[nt],
                                                                  acc[mt][nt], 0, 0, 0);
        __builtin_amdgcn_sched_barrier(0);
        __builtin_amdgcn_s_barrier();
        cu = nu; cv = nv;
    }
#undef STG_B

    float b2v[4], w3v[4];
#pragma unroll
    for (int nt = 0; nt < 4; ++nt) {
        int col = col0 + wc * 64 + nt * 16 + l15;
        b2v[nt] = b2[col];
        w3v[nt] = W3f[col];
    }
#pragma unroll
    for (int mt = 0; mt < 2; ++mt)
#pragma unroll
    for (int r = 0; r < 4; ++r) {
        int rloc = wr * 32 + mt * 16 + lk * 4 + r;
        float p = 0.f;
#pragma unroll
        for (int nt = 0; nt < 4; ++nt)
            p += fmaxf(acc[mt][nt][r] + b2v[nt], 0.f) * w3v[nt];
        p += __shfl_xor(p, 1); p += __shfl_xor(p, 2);
        p += __shfl_xor(p, 4); p += __shfl_xor(p, 8);
        if (l15 == 0) red[wc][rloc] = p;
    }
    __syncthreads();
    if (tid < 64)
        wpart[cx * BM + row0 + tid] = red[0][tid] + red[1][tid]
                                    + red[2][tid] + red[3][tid];
}

// ---------------------------------------------------------------------------
// compute A-row for image b into Al[1024] (x-major) from wpart; sigmoid fused.
__device__ __forceinline__ void compute_A(const float* __restrict__ wpart, float b3v,
                                          int b, float* Al, int t)
{
    for (int i = t; i < NH * N_; i += 128) {
        int y = i & 63, x = i >> 6;
        float v = 0.f;
        if (y != x) {
            int j = y - (y > x ? 1 : 0);
            int r = b * M_ + x * 63 + j;
            float s = b3v + wpart[r] + wpart[BM + r];
            v = 1.f / (1.f + expf(-s));
        }
        Al[i] = v;
    }
}

// msg_h[b] = A[b] @ Go[b] (Go = XX[:,1024:2048]); 1D grid 256 (=32 img x 8 ch)
__global__ __launch_bounds__(128)
void msgh_kernel(const float* __restrict__ wpart, const float* __restrict__ b3,
                 const unsigned short* __restrict__ XX,
                 unsigned short* __restrict__ msgh)
{
    __shared__ float Al[NH * N_];
    __shared__ float Gl[N_][128];
    const int wgid = xcd_swz(blockIdx.x, 32);           // 256 = 8*32
    int b = wgid >> 3, c0 = (wgid & 7) * 128, t = threadIdx.x;
    compute_A(wpart, b3[0], b, Al, t);
    for (int y = 0; y < N_; ++y)
        Gl[y][t] = bf2f(XX[((size_t)(b * 64 + y)) * 3072 + 1024 + c0 + t]);
    __syncthreads();
    for (int x = 0; x < NH; ++x) {
        float s = 0.f;
#pragma unroll 8
        for (int y = 0; y < N_; ++y) s += Al[x * N_ + y] * Gl[y][t];
        msgh[((size_t)(b * NH + x)) * REP + c0 + t] = f2bf(s);
    }
}

// ---------------------------------------------------------------------------
// 64x64-tile bf16 MFMA GEMM for small shapes; BK=32, block 256 (4 waves 32x32).
// ---------------------------------------------------------------------------
__global__ __launch_bounds__(256)
void gemm_small(const unsigned short* __restrict__ A1, const unsigned short* __restrict__ A2,
                const unsigned short* __restrict__ Bt, const float* __restrict__ bias,
                unsigned short* __restrict__ Cb, int K, int Nc, int doRelu, int mode)
{
    __shared__ unsigned short As[4][64 * 32];
    __shared__ unsigned short Bs[4][64 * 32];
    const int tid  = threadIdx.x;
    const int lane = tid & 63, wave = tid >> 6;
    const int wr = wave & 1, wc = wave >> 1;
    const int l15 = lane & 15, lk = lane >> 4;
    const int wgid = xcd_swz(blockIdx.x, 16);           // 128 = 8*16
    const int row0 = (wgid & 7) * 64, col0 = (wgid >> 3) * 64;
    const int kq = (lane & 3) * 8;

    int tr = wave * 16 + (lane >> 2);   // 0..63
    int rr = row0 + tr;
    const unsigned short* p1;
    const unsigned short* p2 = nullptr;
    if (mode == MD_DIRECT) {
        p1 = A1 + (size_t)rr * K;
    } else {            // MD_CC1
        int b = rr >> 4, x = rr & 15;
        p1 = A1 + (size_t)(b * 64 + x) * 1024;
        p2 = A2 + (size_t)rr * 1024 - 1024;
    }
    const unsigned short* pA1 = p1 + kq;
    const unsigned short* pA2 = p2 ? p2 + kq : nullptr;
    const unsigned short* pB  = Bt + (size_t)(col0 + tr) * K + kq;
    const int stO = wave * 512 + lane * 8;
    const int kSw = (mode != MD_DIRECT) ? 1024 : K;
    const int NT = K >> 5;

#define STG_MID(slot, k0) do {                                  \
        const unsigned short* ap = ((k0) < kSw) ? pA1 : pA2;    \
        gld16(ap + (k0), &As[slot][stO]);                       \
        gld16(pB + (k0), &Bs[slot][stO]); } while (0)

    f32x4 acc[2][2];
#pragma unroll
    for (int i = 0; i < 2; ++i)
#pragma unroll
    for (int j = 0; j < 2; ++j) acc[i][j] = (f32x4)0.f;

    STG_MID(0, 0);
    STG_MID(1, 32);
    STG_MID(2, 64);
    for (int t = 0; t < NT; ++t) {
        const int slot = t & 3;
        if (t + 3 < NT) STG_MID((t + 3) & 3, (t + 3) * 32);
        int rem = NT - 1 - t;
        wait_vm(rem >= 3 ? 6 : rem * 2);
        __builtin_amdgcn_s_barrier();
        __builtin_amdgcn_sched_barrier(0);
        bhalf8 af[2], bf4[2];
#pragma unroll
        for (int mt = 0; mt < 2; ++mt)
            af[mt] = *(bhalf8*)&As[slot][(wr * 32 + mt * 16 + l15) * 32 + lk * 8];
#pragma unroll
        for (int nt = 0; nt < 2; ++nt)
            bf4[nt] = *(bhalf8*)&Bs[slot][(wc * 32 + nt * 16 + l15) * 32 + lk * 8];
#pragma unroll
        for (int mt = 0; mt < 2; ++mt)
#pragma unroll
        for (int nt = 0; nt < 2; ++nt)
            acc[mt][nt] = __builtin_amdgcn_mfma_f32_16x16x32_bf16(af[mt], bf4[nt],
                                                                  acc[mt][nt], 0, 0, 0);
        __builtin_amdgcn_sched_barrier(0);
        __builtin_amdgcn_s_barrier();
    }
#undef STG_MID

#pragma unroll
    for (int mt = 0; mt < 2; ++mt)
#pragma unroll
    for (int r = 0; r < 4; ++r) {
        int row = row0 + wr * 32 + mt * 16 + lk * 4 + r;
#pragma unroll
        for (int nt = 0; nt < 2; ++nt) {
            int col = col0 + wc * 32 + nt * 16 + l15;
            float v = acc[mt][nt][r];
            if (bias) v += bias[col];
            if (doRelu) v = fmaxf(v, 0.f);
            Cb[(size_t)row * Nc + col] = f2bf(v);
        }
    }
}

// ---------------------------------------------------------------------------
// Fused final GEMM:
//   encOut[b*64+n] = concat(enc_upd)[n] @ Wou_top  +  A[b]^T @ (Gs[b] @ Wou_bot)
// 1D grid 512 (=32 img x 16 col); XCD swizzle image-major (4 images/XCD).
// ---------------------------------------------------------------------------
__global__ __launch_bounds__(256)
void gemm_cc2(const unsigned short* __restrict__ enc,
              const unsigned short* __restrict__ ench,
              const unsigned short* __restrict__ Gs,
              const unsigned short* __restrict__ Wout,
              const float* __restrict__ wpart, const float* __restrict__ b3,
              float* __restrict__ Cf, unsigned short* __restrict__ Cb)
{
    __shared__ unsigned short As[3][64 * 32];
    __shared__ unsigned short Bt[3][64 * 32];
    __shared__ unsigned short Bb[3][64 * 32];
    __shared__ unsigned short GsL[16][1056];    // 2112B row stride -> 2-way banks
    __shared__ float Al[16][64];
    __shared__ float gsl[16][68];

    const int tid  = threadIdx.x;
    const int lane = tid & 63, wave = tid >> 6;
    const int wr = wave & 1, wc = wave >> 1;
    const int l15 = lane & 15, lk = lane >> 4;
    const int wgid = xcd_swz(blockIdx.x, 64);           // 512 = 8*64
    const int b = wgid >> 4, col0 = (wgid & 15) * 64;
    const int kq = (lane & 3) * 8;

    // ---- prologue: stage Gs[b] (16x1024, padded) + compute A[b] ----
#pragma unroll
    for (int j = 0; j < 8; ++j) {
        int idx = j * 256 + tid;            // 0..2047 uint4s
        int row = idx >> 7, c8 = (idx & 127) * 8;
        uint4 v = *(const uint4*)(Gs + ((size_t)(b * 16 + row)) * 1024 + c8);
        *(uint4*)&GsL[row][c8] = v;
    }
    float b3v = b3[0];
#pragma unroll
    for (int j = 0; j < 4; ++j) {
        int i = j * 256 + tid;              // 0..1023
        int y = i & 63, x = i >> 6;
        float v = 0.f;
        if (y != x) {
            int jj = y - (y > x ? 1 : 0);
            int r = b * M_ + x * 63 + jj;
            float s = b3v + wpart[r] + wpart[BM + r];
            v = 1.f / (1.f + expf(-s));
        }
        Al[x][y] = v;
    }
    asm volatile("s_waitcnt lgkmcnt(0)" ::: "memory");   // own LDS writes done

    int tr = wave * 16 + (lane >> 2);       // 0..63 (= n)
    const unsigned short* pA = (tr < 16 ? ench + ((size_t)(b * 16 + tr)) * 1024
                                        : enc  + ((size_t)(b * 64 + tr)) * 1024) + kq;
    const unsigned short* pBt = Wout + (size_t)(col0 + tr) * 2048 + kq;
    const unsigned short* pBb = pBt + 1024;
    const int stO = wave * 512 + lane * 8;

#define STG_C2(slot, k0) do {                      \
        gld16(pA  + (k0), &As[slot][stO]);         \
        gld16(pBt + (k0), &Bt[slot][stO]);         \
        gld16(pBb + (k0), &Bb[slot][stO]); } while (0)

    f32x4 acc[2][2];
    f32x4 accg[2];
#pragma unroll
    for (int i = 0; i < 2; ++i) {
        accg[i] = (f32x4)0.f;
#pragma unroll
        for (int j = 0; j < 2; ++j) acc[i][j] = (f32x4)0.f;
    }

    STG_C2(0, 0);
    STG_C2(1, 32);
    for (int t = 0; t < 32; ++t) {
        const int slot = t % 3;
        if (t + 2 < 32) STG_C2((t + 2) % 3, (t + 2) * 32);
        wait_vm(t < 30 ? 6 : (t == 30 ? 3 : 0));
        __builtin_amdgcn_s_barrier();
        __builtin_amdgcn_sched_barrier(0);
        bhalf8 af[2], bt4[2], bb4[2], ags;
#pragma unroll
        for (int mt = 0; mt < 2; ++mt)
            af[mt] = *(bhalf8*)&As[slot][(wr * 32 + mt * 16 + l15) * 32 + lk * 8];
#pragma unroll
        for (int nt = 0; nt < 2; ++nt) {
            bt4[nt] = *(bhalf8*)&Bt[slot][(wc * 32 + nt * 16 + l15) * 32 + lk * 8];
            bb4[nt] = *(bhalf8*)&Bb[slot][(wc * 32 + nt * 16 + l15) * 32 + lk * 8];
        }
        ags = *(bhalf8*)&GsL[l15][t * 32 + lk * 8];
#pragma unroll
        for (int mt = 0; mt < 2; ++mt)
#pragma unroll
        for (int nt = 0; nt < 2; ++nt)
            acc[mt][nt] = __builtin_amdgcn_mfma_f32_16x16x32_bf16(af[mt], bt4[nt],
                                                                  acc[mt][nt], 0, 0, 0);
#pragma unroll
        for (int nt = 0; nt < 2; ++nt)
            accg[nt] = __builtin_amdgcn_mfma_f32_16x16x32_bf16(ags, bb4[nt],
                                                               accg[nt], 0, 0, 0);
        __builtin_amdgcn_sched_barrier(0);
        __builtin_amdgcn_s_barrier();
    }
#undef STG_C2

    // GsW = Gs[b] @ Wou_bot for this block's 64 cols -> LDS
    if (wr == 0) {
#pragma unroll
        for (int nt = 0; nt < 2; ++nt)
#pragma unroll
        for (int r = 0; r < 4; ++r)
            gsl[lk * 4 + r][wc * 32 + nt * 16 + l15] = accg[nt][r];
    }
    __syncthreads();

    // epilogue: acc += A^T · GsW (rank-16), then write
#pragma unroll
    for (int x = 0; x < 16; ++x) {
        float g0 = gsl[x][wc * 32 + l15];
        float g1 = gsl[x][wc * 32 + 16 + l15];
#pragma unroll
        for (int mt = 0; mt < 2; ++mt)
#pragma unroll
        for (int r = 0; r < 4; ++r) {
            float a = Al[x][wr * 32 + mt * 16 + lk * 4 + r];
            acc[mt][0][r] += a * g0;
            acc[mt][1][r] += a * g1;
        }
    }
#pragma unroll
    for (int mt = 0; mt < 2; ++mt)
#pragma unroll
    for (int r = 0; r < 4; ++r) {
        size_t row = (size_t)b * 64 + wr * 32 + mt * 16 + lk * 4 + r;
#pragma unroll
        for (int nt = 0; nt < 2; ++nt) {
            int col = col0 + wc * 32 + nt * 16 + l15;
            float v = acc[mt][nt][r];
            if (Cf) Cf[row * 1024 + col] = v;
            else    Cb[row * 1024 + col] = f2bf(v);
        }
    }
}

// ---------------------------------------------------------------------------
// fused tail outputs: pair gather (out0), coords (out1/out2), prior (out3)
__device__ __forceinline__ float lis_f(float x)
{
    return 8.3f / (1.f + expf(12.f - 10.f * x));
}

__global__ __launch_bounds__(256)
void outputs_all(const float* __restrict__ enc, const float* __restrict__ coords,
                 const float* __restrict__ wpart, const float* __restrict__ b3,
                 const int* __restrict__ labels, const float* __restrict__ scores,
                 float* __restrict__ out0, float* __restrict__ out1,
                 float* __restrict__ out2, float* __restrict__ out3)
{
    int bx = blockIdx.x;
    if (bx < 64512) {                       // pair features: BM*512 float4
        int i = bx * 256 + threadIdx.x;
        int r = i >> 9, q = i & 511;
        int b = r / M_, m = r % M_;
        int x = m / 63, j = m % 63;
        int y = j + (j >= x ? 1 : 0);
        const float4* e4 = (const float4*)enc;
        float4 v = (q < 256) ? e4[(b * 64 + x) * 256 + q]
                             : e4[(b * 64 + y) * 256 + (q - 256)];
        ((float4*)out0)[i] = v;
    } else if (bx < 64638) {                // coords: BM rows
        int r = (bx - 64512) * 256 + threadIdx.x;
        int b = r / M_, m = r % M_;
        int x = m / 63, j = m % 63;
        int y = j + (j >= x ? 1 : 0);
        const float4* c4 = (const float4*)coords;
        ((float4*)out1)[r] = c4[b * 64 + x];
        ((float4*)out2)[r] = c4[b * 64 + y];
    } else {                                // prior: BM*117 floats
        int i = (bx - 64638) * 256 + threadIdx.x;
        int r = i / NCLS, c = i % NCLS;
        int b = r / M_, m = r % M_;
        int x = m / 63, j = m % 63;
        int y = j + (j >= x ? 1 : 0);
        int lab = labels[b * 64 + y];
        float val = 0.f;
        if (c == lab) {
            float w = b3[0] + wpart[r] + wpart[BM + r];
            float A = 1.f / (1.f + expf(-w));
            float sx = scores[b * 64 + x], sy = scores[b * 64 + y];
            val = A * lis_f(sx) * lis_f(sy);
        }
        out3[i] = val;
    }
}

// ---------------------------------------------------------------------------
extern "C" void kernel_launch(void* const* d_in, const int* in_sizes, int n_in,
                              void* d_out, int out_size, void* d_ws, size_t ws_size,
                              hipStream_t stream)
{
    const float* box_features = (const float*)d_in[0];
    const float* box_coords   = (const float*)d_in[1];
    const int*   box_labels   = (const int*)d_in[2];
    const float* box_scores   = (const float*)d_in[3];
    const float* W1  = (const float*)d_in[4];
    const float* b1  = (const float*)d_in[5];
    const float* W2  = (const float*)d_in[6];
    const float* b2  = (const float*)d_in[7];
    const float* W3  = (const float*)d_in[8];
    const float* b3  = (const float*)d_in[9];
    const float* Ws  = (const float*)d_in[10];
    const float* bs  = (const float*)d_in[11];
    const float* Wo  = (const float*)d_in[12];
    const float* bo  = (const float*)d_in[13];
    const float* Wsu = (const float*)d_in[14];
    const float* Wou = (const float*)d_in[15];

    float* wsf  = (float*)d_ws;
    float* encA = wsf;           wsf += (size_t)B_ * N_ * R_;    // fp32 final enc
    float* wpart= wsf;           wsf += (size_t)2 * BM;          // 2 col-partials
    float* biasFull = wsf;       wsf += 3072;

    unsigned short* wsu = (unsigned short*)wsf;
    unsigned short* enc0bf = wsu;  wsu += (size_t)B_ * N_ * R_;     // 2M
    unsigned short* encIbf = wsu;  wsu += (size_t)B_ * N_ * R_;     // 2M
    unsigned short* XX     = wsu;  wsu += (size_t)B_ * N_ * 3072;   // 6.3M
    unsigned short* msghbf = wsu;  wsu += (size_t)B_ * NH * REP;    // 0.5M
    unsigned short* enchbf = wsu;  wsu += (size_t)B_ * NH * R_;     // 0.5M
    unsigned short* Gsbf   = wsu;  wsu += (size_t)B_ * NH * REP;    // 0.5M
    unsigned short* Wfused = wsu;  wsu += (size_t)3072 * 1024;
    unsigned short* W2t    = wsu;  wsu += (size_t)512 * 1024;
    unsigned short* Wst    = wsu;  wsu += (size_t)1024 * 1024;
    unsigned short* Wsut   = wsu;  wsu += (size_t)1024 * 2048;
    unsigned short* Wout   = wsu;  wsu += (size_t)1024 * 2048;

    float* out0 = (float*)d_out;                       // pair [32256, 2048]
    float* out1 = out0 + (size_t)BM * 2048;            // bh   [32,1008,4]
    float* out2 = out1 + (size_t)BM * 4;               // bo   [32,1008,4]
    float* out3 = out2 + (size_t)BM * 4;               // prior[32256, 117]

    // ---- prep (1 dispatch: weights + bias + input convert) ----
    prep_all<<<9740, 256, 0, stream>>>(W1, W2, Wo, Ws, Wsu, Wou, bo, b1, box_features,
                                       Wfused, W2t, Wst, Wsut, Wout, biasFull, enc0bf);

    for (int it = 0; it < 2; ++it) {
        const unsigned short* enc = (it == 0) ? enc0bf : encIbf;
        // XX = enc @ [W1bot | Wo] (all rows) | W1top (human rows only)
        gemm_uvgo<<<288, 256, 0, stream>>>(enc, Wfused, biasFull, XX);
        // one-pass fused pair MLP (TLP variant) -> wpart (2 partials)
        pair_bf<<<1008, 512, 0, stream>>>(XX, W2t, b2, W3, wpart);
        // msgh = A @ Go  (A recomputed from wpart)
        msgh_kernel<<<256, 128, 0, stream>>>(wpart, b3, XX, msghbf);
        // ench = concat(enc[humans], msgh) @ Wsu
        gemm_small<<<128, 256, 0, stream>>>(enc, msghbf, Wsut, nullptr,
                                            enchbf, 2048, 1024, 0, MD_CC1);
        // Gs = relu(ench @ Ws + bs)
        gemm_small<<<128, 256, 0, stream>>>(enchbf, nullptr, Wst, bs,
                                            Gsbf, 1024, 1024, 1, MD_DIRECT);
        // encOut = enc_upd @ Wou_top + A^T @ (Gs @ Wou_bot)   (fused, K=1024)
        gemm_cc2<<<512, 256, 0, stream>>>(enc, enchbf, Gsbf, Wout, wpart, b3,
                                          (it == 1) ? encA : nullptr,
                                          (it == 0) ? encIbf : nullptr);
    }

    // fused tail outputs (pair gather + coords + prior) — 1 dispatch
    outputs_all<<<79380, 256, 0, stream>>>(encA, box_coords, wpart, b3,
                                           box_labels, box_scores,
                                           out0, out1, out2, out3);
}

// Round 9
// 658.705 us; speedup vs baseline: 1.0267x; 1.0267x over previous
//
#include <hip/hip_runtime.h>

#define B_   32
#define N_   64
#define NH   16
#define R_   1024
#define REP  1024
#define M_   1008           // 16*63
#define BM   (B_ * M_)      // 32256
#define NCLS 117

#define MD_DIRECT 0
#define MD_CC1    2   // k<1024: enc[b*64+x]; k>=1024: msgh[row]      (512 rows)

typedef short bhalf8 __attribute__((ext_vector_type(8)));   // 8 bf16 (4 VGPRs)
typedef float f32x4  __attribute__((ext_vector_type(4)));   // MFMA acc

typedef __attribute__((address_space(3))) void       lds_t;
typedef const __attribute__((address_space(1))) void gbl_t;
__device__ __forceinline__ void gld16(const void* g, void* l)
{
    __builtin_amdgcn_global_load_lds((gbl_t*)g, (lds_t*)l, 16, 0, 0);
}

// bijective XCD swizzle (grid = 8q): XCD k gets contiguous wgid [k*q,(k+1)*q)
__device__ __forceinline__ int xcd_swz(int orig, int q)
{
    return (orig & 7) * q + (orig >> 3);
}
// general bijective form (grid = 8q + r, m204)
__device__ __forceinline__ int xcd_swz_gen(int orig, int q, int r)
{
    int x = orig & 7, o = orig >> 3;
    return (x < r ? x * (q + 1) : r * (q + 1) + (x - r) * q) + o;
}

__device__ __forceinline__ unsigned short f2bf(float f)
{
    union { float f; unsigned int u; } x; x.f = f;
    unsigned int r = x.u + 0x7FFFu + ((x.u >> 16) & 1u);    // round-nearest-even
    return (unsigned short)(r >> 16);
}
__device__ __forceinline__ float bf2f(unsigned short u)
{
    union { unsigned int i; float f; } x; x.i = ((unsigned int)u) << 16; return x.f;
}

// packed add+relu+pack via v_cvt_pk_bf16_f32
__device__ __forceinline__ unsigned int addrelu2(unsigned int a, unsigned int b)
{
    union { unsigned int u; float f; } la, ha, lb, hb;
    la.u = a << 16;          ha.u = a & 0xffff0000u;
    lb.u = b << 16;          hb.u = b & 0xffff0000u;
    float lo = fmaxf(la.f + lb.f, 0.f);
    float hi = fmaxf(ha.f + hb.f, 0.f);
    unsigned int r;
    asm("v_cvt_pk_bf16_f32 %0, %1, %2" : "=v"(r) : "v"(lo), "v"(hi));
    return r;
}

// counted waits (immediates must be literals -> uniform branch ladder)
__device__ __forceinline__ void wait_vm(int n)
{
    if (n >= 8)      asm volatile("s_waitcnt vmcnt(8)" ::: "memory");
    else if (n == 6) asm volatile("s_waitcnt vmcnt(6)" ::: "memory");
    else if (n == 4) asm volatile("s_waitcnt vmcnt(4)" ::: "memory");
    else if (n == 3) asm volatile("s_waitcnt vmcnt(3)" ::: "memory");
    else if (n == 2) asm volatile("s_waitcnt vmcnt(2)" ::: "memory");
    else             asm volatile("s_waitcnt vmcnt(0)" ::: "memory");
}

// ---------------------------------------------------------------------------
// One-dispatch weight prep + bf16 input convert.
// ---------------------------------------------------------------------------
__device__ __forceinline__ void tr32(const float* in, unsigned short* out,
                                     int K, int N, int local)
{
    __shared__ float t[32][33];
    int kb = K >> 5;
    int k0 = (local % kb) * 32, n0 = (local / kb) * 32;
    int tx = threadIdx.x & 31, ty = threadIdx.x >> 5;
#pragma unroll
    for (int r = 0; r < 4; ++r)
        t[ty + r * 8][tx] = in[(size_t)(k0 + ty + r * 8) * N + n0 + tx];
    __syncthreads();
    // packed u32 writes (2 bf16/store, 4x fewer store instrs): 512 u32, 2/thread
    unsigned int* o32 = (unsigned int*)(out + (size_t)n0 * K + k0);
#pragma unroll
    for (int w = 0; w < 2; ++w) {
        int u = threadIdx.x * 2 + w;            // 0..511
        int n = u >> 4, c = (u & 15) * 2;
        unsigned int val = (unsigned)f2bf(t[c][n]) | ((unsigned)f2bf(t[c + 1][n]) << 16);
        o32[(size_t)n * (K >> 1) + (u & 15)] = val;
    }
}

__global__ __launch_bounds__(256)
void prep_all(const float* __restrict__ W1, const float* __restrict__ W2,
              const float* __restrict__ Wo, const float* __restrict__ Ws,
              const float* __restrict__ Wsu, const float* __restrict__ Wou,
              const float* __restrict__ bo_, const float* __restrict__ b1_,
              const float* __restrict__ feat,
              unsigned short* __restrict__ Wfused, unsigned short* __restrict__ W2t,
              unsigned short* __restrict__ Wst, unsigned short* __restrict__ Wsut,
              unsigned short* __restrict__ Wout, float* __restrict__ biasFull,
              unsigned short* __restrict__ enc0bf)
{
    int bx = blockIdx.x;
    if      (bx < 1024) tr32(W1 + 1024 * 1024, Wfused,               1024, 1024, bx);
    else if (bx < 2048) tr32(Wo,               Wfused + 1024 * 1024, 1024, 1024, bx - 1024);
    else if (bx < 3072) tr32(W1,               Wfused + 2048 * 1024, 1024, 1024, bx - 2048);
    else if (bx < 3584) tr32(W2,  W2t,  1024, 512,  bx - 3072);
    else if (bx < 4608) tr32(Ws,  Wst,  1024, 1024, bx - 3584);
    else if (bx < 6656) tr32(Wsu, Wsut, 2048, 1024, bx - 4608);
    else if (bx < 8704) tr32(Wou, Wout, 2048, 1024, bx - 6656);
    else if (bx < 8716) {
        int c = (bx - 8704) * 256 + threadIdx.x;   // 0..3071
        float v = 0.f;
        if (c >= 2048)      v = b1_[c - 2048];
        else if (c >= 1024) v = bo_[c - 1024];
        biasFull[c] = v;
    } else {
        int i = (bx - 8716) * 256 + threadIdx.x;   // over 2M/8 = 256K
        float4 a = ((const float4*)feat)[2 * i];
        float4 b = ((const float4*)feat)[2 * i + 1];
        uint4 o;
        o.x = (unsigned)f2bf(a.x) | ((unsigned)f2bf(a.y) << 16);
        o.y = (unsigned)f2bf(a.z) | ((unsigned)f2bf(a.w) << 16);
        o.z = (unsigned)f2bf(b.x) | ((unsigned)f2bf(b.y) << 16);
        o.w = (unsigned)f2bf(b.z) | ((unsigned)f2bf(b.w) << 16);
        ((uint4*)enc0bf)[i] = o;
    }
}

// ---------------------------------------------------------------------------
// Fused U/V/Go GEMM.  Two sections in one dispatch (grid 288 = 8*36):
//  wgid < 256 : V|Go  — XX[:, 0..2047]  = enc(all 2048 rows) @ Wf[0..2047]^T
//  wgid >=256 : U     — XX[human rows, 2048..3071] only.
// 128x128 tile, BK=32, block 256.
// ---------------------------------------------------------------------------
__global__ __launch_bounds__(256)
void gemm_uvgo(const unsigned short* __restrict__ enc,
               const unsigned short* __restrict__ Wf,
               const float* __restrict__ biasFull, unsigned short* __restrict__ XX)
{
    __shared__ unsigned short As[3][128 * 32];
    __shared__ unsigned short Bs[3][128 * 32];
    const int tid  = threadIdx.x;
    const int lane = tid & 63, wave = tid >> 6;
    const int wm = wave & 1, wn = wave >> 1;
    const int l15 = lane & 15, lk = lane >> 4;
    const int wgid = xcd_swz(blockIdx.x, 36);           // 288 = 8*36
    const int uSec = wgid >= 256;
    int row0, col0;
    if (!uSec) { row0 = (wgid & 15) * 128;       col0 = (wgid >> 4) * 128; }
    else       { int idx = wgid - 256;
                 row0 = (idx & 3) * 128;         col0 = 2048 + (idx >> 2) * 128; }
    const int kq = (lane & 3) * 8;

    const unsigned short* pA[2];
    const unsigned short* pB[2];
    int ldsOff[2];
#pragma unroll
    for (int i = 0; i < 2; ++i) {
        int tr = wave * 32 + (lane >> 2) + i * 16;
        int grow;
        if (!uSec) grow = row0 + tr;
        else { int hr = row0 + tr; grow = (hr >> 4) * 64 + (hr & 15); }
        pA[i]  = enc + (size_t)grow * 1024 + kq;
        pB[i]  = Wf  + (size_t)(col0 + tr) * 1024 + kq;
        ldsOff[i] = wave * 1024 + i * 512 + lane * 8;
    }

#define STG_UV(slot, k0) do {                          \
        gld16(pA[0] + (k0), &As[slot][ldsOff[0]]);     \
        gld16(pA[1] + (k0), &As[slot][ldsOff[1]]);     \
        gld16(pB[0] + (k0), &Bs[slot][ldsOff[0]]);     \
        gld16(pB[1] + (k0), &Bs[slot][ldsOff[1]]); } while (0)

    f32x4 acc[4][4];
#pragma unroll
    for (int i = 0; i < 4; ++i)
#pragma unroll
    for (int j = 0; j < 4; ++j) acc[i][j] = (f32x4)0.f;

    STG_UV(0, 0);
    STG_UV(1, 32);
    for (int t = 0; t < 32; ++t) {
        const int slot = t % 3;
        if (t + 2 < 32) STG_UV((t + 2) % 3, (t + 2) * 32);
        wait_vm(t < 30 ? 8 : (t == 30 ? 4 : 0));
        __builtin_amdgcn_s_barrier();
        __builtin_amdgcn_sched_barrier(0);
        bhalf8 af[4], bf4[4];
#pragma unroll
        for (int mt = 0; mt < 4; ++mt)
            af[mt] = *(bhalf8*)&As[slot][(wm * 64 + mt * 16 + l15) * 32 + lk * 8];
#pragma unroll
        for (int nt = 0; nt < 4; ++nt)
            bf4[nt] = *(bhalf8*)&Bs[slot][(wn * 64 + nt * 16 + l15) * 32 + lk * 8];
#pragma unroll
        for (int mt = 0; mt < 4; ++mt)
#pragma unroll
        for (int nt = 0; nt < 4; ++nt)
            acc[mt][nt] = __builtin_amdgcn_mfma_f32_16x16x32_bf16(af[mt], bf4[nt],
                                                                  acc[mt][nt], 0, 0, 0);
        __builtin_amdgcn_sched_barrier(0);
        __builtin_amdgcn_s_barrier();
    }
#undef STG_UV

#pragma unroll
    for (int mt = 0; mt < 4; ++mt)
#pragma unroll
    for (int r = 0; r < 4; ++r) {
        int lrow = row0 + wm * 64 + mt * 16 + lk * 4 + r;
        int row = uSec ? ((lrow >> 4) * 64 + (lrow & 15)) : lrow;
#pragma unroll
        for (int nt = 0; nt < 4; ++nt) {
            int col = col0 + wn * 64 + nt * 16 + l15;
            float v = acc[mt][nt][r] + biasFull[col];
            if ((col >> 10) == 1) v = fmaxf(v, 0.f);    // Go region
            XX[(size_t)row * 3072 + col] = f2bf(v);
        }
    }
}

// ---------------------------------------------------------------------------
// One-pass fused pair MLP, 8-PHASE schedule (T3+T4+T5): each K-step (BK=32)
// split into 4 phases of {2 ds_read B-subtiles | 1 staging issue -> barrier ->
// lgkmcnt(0) -> setprio(1) -> 8 MFMA -> setprio(0) -> barrier}.  A double-
// buffered (write A(t+1) in phase 3, lgkm-drained pre-barrier).  Counted vmcnt
// ONCE per K-step (steady vmcnt(3), never 0 mid-loop).  Exact ledger:
// leftover{STG123(t+1)}=3 +STG0(t+2) +regs(2) +STG1/2/3(t+2) = 9 -> drain to 3.
// 512 threads / 8 waves (2 row x 4 col), 128 rows x 512 cols, grid 252.
// ---------------------------------------------------------------------------
__global__ __launch_bounds__(512)
void pair_bf(const unsigned short* __restrict__ XX,
             const unsigned short* __restrict__ W2t, const float* __restrict__ b2,
             const float* __restrict__ W3f, float* __restrict__ wpart)
{
    __shared__ unsigned short As[2][128 * 32];          // 16 KB (A dbuf)
    __shared__ unsigned short Bs[3][512 * 32];          // 96 KB
    __shared__ float red[4][128];
    const int tid  = threadIdx.x;
    const int lane = tid & 63, wave = tid >> 6;
    const int wm = wave & 1, wn = wave >> 1;            // 2 x 4
    const int l15 = lane & 15, lk = lane >> 4;
    const int wgid = xcd_swz_gen(blockIdx.x, 31, 4);    // 252 blocks
    const int row0 = wgid * 128;

    // A-staging: 4 threads per row, 16B each
    const int srow = tid >> 2, skq = (tid & 3) * 8;
    int rg = row0 + srow;
    int b  = rg / M_, m = rg % M_;
    int x  = m / 63, jj = m % 63;
    int y  = jj + (jj >= x ? 1 : 0);
    const unsigned short* Up = XX + ((size_t)(b * 64 + x)) * 3072 + 2048 + skq;
    const unsigned short* Vp = XX + ((size_t)(b * 64 + y)) * 3072 + skq;
    const int aw = srow * 32 + skq;

    const int kq = (lane & 3) * 8;
    const unsigned short* pB[4];
    int bO[4];
#pragma unroll
    for (int i = 0; i < 4; ++i) {
        int trB = wave * 64 + i * 16 + (lane >> 2);     // 0..511
        pB[i] = W2t + (size_t)trB * REP + kq;
        bO[i] = wave * 2048 + i * 512 + lane * 8;
    }

    f32x4 acc[4][8];
#pragma unroll
    for (int i = 0; i < 4; ++i)
#pragma unroll
    for (int j = 0; j < 8; ++j) acc[i][j] = (f32x4)0.f;

#define MFMA_PAIR(n0, n1)                                                       \
    do {                                                                        \
        _Pragma("unroll")                                                       \
        for (int mt = 0; mt < 4; ++mt) {                                        \
            acc[mt][n0] = __builtin_amdgcn_mfma_f32_16x16x32_bf16(af[mt], bq0,  \
                                                         acc[mt][n0], 0, 0, 0); \
            acc[mt][n1] = __builtin_amdgcn_mfma_f32_16x16x32_bf16(af[mt], bq1,  \
                                                         acc[mt][n1], 0, 0, 0); \
        }                                                                       \
    } while (0)

#define PHASE_MFMA(n0, n1)                              \
    do {                                                \
        __builtin_amdgcn_s_barrier();                   \
        asm volatile("s_waitcnt lgkmcnt(0)" ::: "memory"); \
        __builtin_amdgcn_sched_barrier(0);              \
        __builtin_amdgcn_s_setprio(1);                  \
        MFMA_PAIR(n0, n1);                              \
        __builtin_amdgcn_s_setprio(0);                  \
        __builtin_amdgcn_sched_barrier(0);              \
        __builtin_amdgcn_s_barrier();                   \
    } while (0)

    // ---- prologue: regs(0), stage slots 0,1, build A(0) ----
    uint4 cu = *(const uint4*)(Up);
    uint4 cv = *(const uint4*)(Vp);
#pragma unroll
    for (int i = 0; i < 4; ++i) gld16(pB[i], &Bs[0][bO[i]]);
#pragma unroll
    for (int i = 0; i < 4; ++i) gld16(pB[i] + 32, &Bs[1][bO[i]]);
    asm volatile("s_waitcnt vmcnt(8)" ::: "memory");    // drain regs(0)
    {
        uint4 h;
        h.x = addrelu2(cu.x, cv.x); h.y = addrelu2(cu.y, cv.y);
        h.z = addrelu2(cu.z, cv.z); h.w = addrelu2(cu.w, cv.w);
        *(uint4*)&As[0][aw] = h;
    }
    asm volatile("s_waitcnt vmcnt(4) lgkmcnt(0)" ::: "memory");  // B(0)+A-write done
    __builtin_amdgcn_s_barrier();

    for (int t = 0; t < 32; ++t) {
        const unsigned short* Bc = Bs[t % 3];
        unsigned short* Bn = (unsigned short*)Bs[(t + 2) % 3];
        const unsigned short* Ac = As[t & 1];
        const bool pf = (t + 2 < 32);
        const int k2 = (t + 2) * 32;
        const int kn = (t + 1 < 32) ? (t + 1) * 32 : 0;

        bhalf8 af[4];
#pragma unroll
        for (int mt = 0; mt < 4; ++mt)
            af[mt] = *(bhalf8*)&Ac[(wm * 64 + mt * 16 + l15) * 32 + lk * 8];

        // ---- phase 0 : nt 0,1 ; STG0(t+2) ; regs(t+1) ----
        bhalf8 bq0 = *(bhalf8*)&Bc[(wn * 128 + 0 * 16 + l15) * 32 + lk * 8];
        bhalf8 bq1 = *(bhalf8*)&Bc[(wn * 128 + 1 * 16 + l15) * 32 + lk * 8];
        if (pf) gld16(pB[0] + k2, &Bn[bO[0]]);
        uint4 nu = *(const uint4*)(Up + kn);
        uint4 nv = *(const uint4*)(Vp + kn);
        PHASE_MFMA(0, 1);

        // ---- phase 1 : nt 2,3 ; STG1(t+2) ----
        bq0 = *(bhalf8*)&Bc[(wn * 128 + 2 * 16 + l15) * 32 + lk * 8];
        bq1 = *(bhalf8*)&Bc[(wn * 128 + 3 * 16 + l15) * 32 + lk * 8];
        if (pf) gld16(pB[1] + k2, &Bn[bO[1]]);
        PHASE_MFMA(2, 3);

        // ---- phase 2 : nt 4,5 ; STG2(t+2) ----
        bq0 = *(bhalf8*)&Bc[(wn * 128 + 4 * 16 + l15) * 32 + lk * 8];
        bq1 = *(bhalf8*)&Bc[(wn * 128 + 5 * 16 + l15) * 32 + lk * 8];
        if (pf) gld16(pB[2] + k2, &Bn[bO[2]]);
        PHASE_MFMA(4, 5);

        // ---- phase 3 : nt 6,7 ; STG3(t+2) ; A(t+1) build ; K-step vmcnt ----
        bq0 = *(bhalf8*)&Bc[(wn * 128 + 6 * 16 + l15) * 32 + lk * 8];
        bq1 = *(bhalf8*)&Bc[(wn * 128 + 7 * 16 + l15) * 32 + lk * 8];
        if (pf) gld16(pB[3] + k2, &Bn[bO[3]]);
        {
            uint4 h;        // compiler auto-inserts vmcnt for nu/nv dependency
            h.x = addrelu2(nu.x, nv.x); h.y = addrelu2(nu.y, nv.y);
            h.z = addrelu2(nu.z, nv.z); h.w = addrelu2(nu.w, nv.w);
            *(uint4*)&As[(t + 1) & 1][aw] = h;
        }
        if (t < 30) asm volatile("s_waitcnt vmcnt(3) lgkmcnt(0)" ::: "memory");
        else        asm volatile("s_waitcnt vmcnt(0) lgkmcnt(0)" ::: "memory");
        __builtin_amdgcn_s_barrier();
        __builtin_amdgcn_sched_barrier(0);
        __builtin_amdgcn_s_setprio(1);
        MFMA_PAIR(6, 7);
        __builtin_amdgcn_s_setprio(0);
        __builtin_amdgcn_sched_barrier(0);
        __builtin_amdgcn_s_barrier();
    }
#undef PHASE_MFMA
#undef MFMA_PAIR

    float b2v[8], w3v[8];
#pragma unroll
    for (int nt = 0; nt < 8; ++nt) {
        int col = wn * 128 + nt * 16 + l15;
        b2v[nt] = b2[col];
        w3v[nt] = W3f[col];
    }
#pragma unroll
    for (int mt = 0; mt < 4; ++mt)
#pragma unroll
    for (int r = 0; r < 4; ++r) {
        int rloc = wm * 64 + mt * 16 + lk * 4 + r;
        float p = 0.f;
#pragma unroll
        for (int nt = 0; nt < 8; ++nt)
            p += fmaxf(acc[mt][nt][r] + b2v[nt], 0.f) * w3v[nt];
        p += __shfl_xor(p, 1); p += __shfl_xor(p, 2);
        p += __shfl_xor(p, 4); p += __shfl_xor(p, 8);
        if (l15 == 0) red[wn][rloc] = p;
    }
    __syncthreads();
    if (tid < 128)
        wpart[row0 + tid] = red[0][tid] + red[1][tid] + red[2][tid] + red[3][tid];
}

// ---------------------------------------------------------------------------
// compute A-row for image b into Al[1024] (x-major) from wpart; sigmoid fused.
__device__ __forceinline__ void compute_A(const float* __restrict__ wpart, float b3v,
                                          int b, float* Al, int t)
{
    for (int i = t; i < NH * N_; i += 128) {
        int y = i & 63, x = i >> 6;
        float v = 0.f;
        if (y != x) {
            int j = y - (y > x ? 1 : 0);
            float s = b3v + wpart[b * M_ + x * 63 + j];
            v = 1.f / (1.f + expf(-s));
        }
        Al[i] = v;
    }
}

// msg_h[b] = A[b] @ Go[b] (Go = XX[:,1024:2048]); 1D grid 256 (=32 img x 8 ch)
__global__ __launch_bounds__(128)
void msgh_kernel(const float* __restrict__ wpart, const float* __restrict__ b3,
                 const unsigned short* __restrict__ XX,
                 unsigned short* __restrict__ msgh)
{
    __shared__ float Al[NH * N_];
    __shared__ float Gl[N_][128];
    const int wgid = xcd_swz(blockIdx.x, 32);           // 256 = 8*32
    int b = wgid >> 3, c0 = (wgid & 7) * 128, t = threadIdx.x;
    compute_A(wpart, b3[0], b, Al, t);
    for (int y = 0; y < N_; ++y)
        Gl[y][t] = bf2f(XX[((size_t)(b * 64 + y)) * 3072 + 1024 + c0 + t]);
    __syncthreads();
    for (int x = 0; x < NH; ++x) {
        float s = 0.f;
#pragma unroll 8
        for (int y = 0; y < N_; ++y) s += Al[x * N_ + y] * Gl[y][t];
        msgh[((size_t)(b * NH + x)) * REP + c0 + t] = f2bf(s);
    }
}

// ---------------------------------------------------------------------------
// 64x64-tile bf16 MFMA GEMM for small shapes; BK=32, block 256 (4 waves 32x32).
// ---------------------------------------------------------------------------
__global__ __launch_bounds__(256)
void gemm_small(const unsigned short* __restrict__ A1, const unsigned short* __restrict__ A2,
                const unsigned short* __restrict__ Bt, const float* __restrict__ bias,
                unsigned short* __restrict__ Cb, int K, int Nc, int doRelu, int mode)
{
    __shared__ unsigned short As[4][64 * 32];
    __shared__ unsigned short Bs[4][64 * 32];
    const int tid  = threadIdx.x;
    const int lane = tid & 63, wave = tid >> 6;
    const int wr = wave & 1, wc = wave >> 1;
    const int l15 = lane & 15, lk = lane >> 4;
    const int wgid = xcd_swz(blockIdx.x, 16);           // 128 = 8*16
    const int row0 = (wgid & 7) * 64, col0 = (wgid >> 3) * 64;
    const int kq = (lane & 3) * 8;

    int tr = wave * 16 + (lane >> 2);   // 0..63
    int rr = row0 + tr;
    const unsigned short* p1;
    const unsigned short* p2 = nullptr;
    if (mode == MD_DIRECT) {
        p1 = A1 + (size_t)rr * K;
    } else {            // MD_CC1
        int b = rr >> 4, x = rr & 15;
        p1 = A1 + (size_t)(b * 64 + x) * 1024;
        p2 = A2 + (size_t)rr * 1024 - 1024;
    }
    const unsigned short* pA1 = p1 + kq;
    const unsigned short* pA2 = p2 ? p2 + kq : nullptr;
    const unsigned short* pB  = Bt + (size_t)(col0 + tr) * K + kq;
    const int stO = wave * 512 + lane * 8;
    const int kSw = (mode != MD_DIRECT) ? 1024 : K;
    const int NT = K >> 5;

#define STG_MID(slot, k0) do {                                  \
        const unsigned short* ap = ((k0) < kSw) ? pA1 : pA2;    \
        gld16(ap + (k0), &As[slot][stO]);                       \
        gld16(pB + (k0), &Bs[slot][stO]); } while (0)

    f32x4 acc[2][2];
#pragma unroll
    for (int i = 0; i < 2; ++i)
#pragma unroll
    for (int j = 0; j < 2; ++j) acc[i][j] = (f32x4)0.f;

    STG_MID(0, 0);
    STG_MID(1, 32);
    STG_MID(2, 64);
    for (int t = 0; t < NT; ++t) {
        const int slot = t & 3;
        if (t + 3 < NT) STG_MID((t + 3) & 3, (t + 3) * 32);
        int rem = NT - 1 - t;
        wait_vm(rem >= 3 ? 6 : rem * 2);
        __builtin_amdgcn_s_barrier();
        __builtin_amdgcn_sched_barrier(0);
        bhalf8 af[2], bf4[2];
#pragma unroll
        for (int mt = 0; mt < 2; ++mt)
            af[mt] = *(bhalf8*)&As[slot][(wr * 32 + mt * 16 + l15) * 32 + lk * 8];
#pragma unroll
        for (int nt = 0; nt < 2; ++nt)
            bf4[nt] = *(bhalf8*)&Bs[slot][(wc * 32 + nt * 16 + l15) * 32 + lk * 8];
#pragma unroll
        for (int mt = 0; mt < 2; ++mt)
#pragma unroll
        for (int nt = 0; nt < 2; ++nt)
            acc[mt][nt] = __builtin_amdgcn_mfma_f32_16x16x32_bf16(af[mt], bf4[nt],
                                                                  acc[mt][nt], 0, 0, 0);
        __builtin_amdgcn_sched_barrier(0);
        __builtin_amdgcn_s_barrier();
    }
#undef STG_MID

#pragma unroll
    for (int mt = 0; mt < 2; ++mt)
#pragma unroll
    for (int r = 0; r < 4; ++r) {
        int row = row0 + wr * 32 + mt * 16 + lk * 4 + r;
#pragma unroll
        for (int nt = 0; nt < 2; ++nt) {
            int col = col0 + wc * 32 + nt * 16 + l15;
            float v = acc[mt][nt][r];
            if (bias) v += bias[col];
            if (doRelu) v = fmaxf(v, 0.f);
            Cb[(size_t)row * Nc + col] = f2bf(v);
        }
    }
}

// ---------------------------------------------------------------------------
// Fused final GEMM:
//   encOut[b*64+n] = concat(enc_upd)[n] @ Wou_top  +  A[b]^T @ (Gs[b] @ Wou_bot)
// 1D grid 512 (=32 img x 16 col); XCD swizzle image-major (4 images/XCD).
// ---------------------------------------------------------------------------
__global__ __launch_bounds__(256)
void gemm_cc2(const unsigned short* __restrict__ enc,
              const unsigned short* __restrict__ ench,
              const unsigned short* __restrict__ Gs,
              const unsigned short* __restrict__ Wout,
              const float* __restrict__ wpart, const float* __restrict__ b3,
              float* __restrict__ Cf, unsigned short* __restrict__ Cb)
{
    __shared__ unsigned short As[3][64 * 32];
    __shared__ unsigned short Bt[3][64 * 32];
    __shared__ unsigned short Bb[3][64 * 32];
    __shared__ unsigned short GsL[16][1056];    // 2112B row stride -> 2-way banks
    __shared__ float Al[16][64];
    __shared__ float gsl[16][68];

    const int tid  = threadIdx.x;
    const int lane = tid & 63, wave = tid >> 6;
    const int wr = wave & 1, wc = wave >> 1;
    const int l15 = lane & 15, lk = lane >> 4;
    const int wgid = xcd_swz(blockIdx.x, 64);           // 512 = 8*64
    const int b = wgid >> 4, col0 = (wgid & 15) * 64;
    const int kq = (lane & 3) * 8;

    // ---- prologue: stage Gs[b] (16x1024, padded) + compute A[b] ----
#pragma unroll
    for (int j = 0; j < 8; ++j) {
        int idx = j * 256 + tid;            // 0..2047 uint4s
        int row = idx >> 7, c8 = (idx & 127) * 8;
        uint4 v = *(const uint4*)(Gs + ((size_t)(b * 16 + row)) * 1024 + c8);
        *(uint4*)&GsL[row][c8] = v;
    }
    float b3v = b3[0];
#pragma unroll
    for (int j = 0; j < 4; ++j) {
        int i = j * 256 + tid;              // 0..1023
        int y = i & 63, x = i >> 6;
        float v = 0.f;
        if (y != x) {
            int jj = y - (y > x ? 1 : 0);
            float s = b3v + wpart[b * M_ + x * 63 + jj];
            v = 1.f / (1.f + expf(-s));
        }
        Al[x][y] = v;
    }
    asm volatile("s_waitcnt lgkmcnt(0)" ::: "memory");   // own LDS writes done

    int tr = wave * 16 + (lane >> 2);       // 0..63 (= n)
    const unsigned short* pA = (tr < 16 ? ench + ((size_t)(b * 16 + tr)) * 1024
                                        : enc  + ((size_t)(b * 64 + tr)) * 1024) + kq;
    const unsigned short* pBt = Wout + (size_t)(col0 + tr) * 2048 + kq;
    const unsigned short* pBb = pBt + 1024;
    const int stO = wave * 512 + lane * 8;

#define STG_C2(slot, k0) do {                      \
        gld16(pA  + (k0), &As[slot][stO]);         \
        gld16(pBt + (k0), &Bt[slot][stO]);         \
        gld16(pBb + (k0), &Bb[slot][stO]); } while (0)

    f32x4 acc[2][2];
    f32x4 accg[2];
#pragma unroll
    for (int i = 0; i < 2; ++i) {
        accg[i] = (f32x4)0.f;
#pragma unroll
        for (int j = 0; j < 2; ++j) acc[i][j] = (f32x4)0.f;
    }

    STG_C2(0, 0);
    STG_C2(1, 32);
    for (int t = 0; t < 32; ++t) {
        const int slot = t % 3;
        if (t + 2 < 32) STG_C2((t + 2) % 3, (t + 2) * 32);
        wait_vm(t < 30 ? 6 : (t == 30 ? 3 : 0));
        __builtin_amdgcn_s_barrier();
        __builtin_amdgcn_sched_barrier(0);
        bhalf8 af[2], bt4[2], bb4[2], ags;
#pragma unroll
        for (int mt = 0; mt < 2; ++mt)
            af[mt] = *(bhalf8*)&As[slot][(wr * 32 + mt * 16 + l15) * 32 + lk * 8];
#pragma unroll
        for (int nt = 0; nt < 2; ++nt) {
            bt4[nt] = *(bhalf8*)&Bt[slot][(wc * 32 + nt * 16 + l15) * 32 + lk * 8];
            bb4[nt] = *(bhalf8*)&Bb[slot][(wc * 32 + nt * 16 + l15) * 32 + lk * 8];
        }
        ags = *(bhalf8*)&GsL[l15][t * 32 + lk * 8];
#pragma unroll
        for (int mt = 0; mt < 2; ++mt)
#pragma unroll
        for (int nt = 0; nt < 2; ++nt)
            acc[mt][nt] = __builtin_amdgcn_mfma_f32_16x16x32_bf16(af[mt], bt4[nt],
                                                                  acc[mt][nt], 0, 0, 0);
#pragma unroll
        for (int nt = 0; nt < 2; ++nt)
            accg[nt] = __builtin_amdgcn_mfma_f32_16x16x32_bf16(ags, bb4[nt],
                                                               accg[nt], 0, 0, 0);
        __builtin_amdgcn_sched_barrier(0);
        __builtin_amdgcn_s_barrier();
    }
#undef STG_C2

    // GsW = Gs[b] @ Wou_bot for this block's 64 cols -> LDS
    if (wr == 0) {
#pragma unroll
        for (int nt = 0; nt < 2; ++nt)
#pragma unroll
        for (int r = 0; r < 4; ++r)
            gsl[lk * 4 + r][wc * 32 + nt * 16 + l15] = accg[nt][r];
    }
    __syncthreads();

    // epilogue: acc += A^T · GsW (rank-16), then write
#pragma unroll
    for (int x = 0; x < 16; ++x) {
        float g0 = gsl[x][wc * 32 + l15];
        float g1 = gsl[x][wc * 32 + 16 + l15];
#pragma unroll
        for (int mt = 0; mt < 2; ++mt)
#pragma unroll
        for (int r = 0; r < 4; ++r) {
            float a = Al[x][wr * 32 + mt * 16 + lk * 4 + r];
            acc[mt][0][r] += a * g0;
            acc[mt][1][r] += a * g1;
        }
    }
#pragma unroll
    for (int mt = 0; mt < 2; ++mt)
#pragma unroll
    for (int r = 0; r < 4; ++r) {
        size_t row = (size_t)b * 64 + wr * 32 + mt * 16 + lk * 4 + r;
#pragma unroll
        for (int nt = 0; nt < 2; ++nt) {
            int col = col0 + wc * 32 + nt * 16 + l15;
            float v = acc[mt][nt][r];
            if (Cf) Cf[row * 1024 + col] = v;
            else    Cb[row * 1024 + col] = f2bf(v);
        }
    }
}

// ---------------------------------------------------------------------------
// fused tail outputs: pair gather (out0), coords (out1/out2), prior (out3)
__device__ __forceinline__ float lis_f(float x)
{
    return 8.3f / (1.f + expf(12.f - 10.f * x));
}

__global__ __launch_bounds__(256)
void outputs_all(const float* __restrict__ enc, const float* __restrict__ coords,
                 const float* __restrict__ wpart, const float* __restrict__ b3,
                 const int* __restrict__ labels, const float* __restrict__ scores,
                 float* __restrict__ out0, float* __restrict__ out1,
                 float* __restrict__ out2, float* __restrict__ out3)
{
    int bx = blockIdx.x;
    if (bx < 64512) {                       // pair features: BM*512 float4
        int i = bx * 256 + threadIdx.x;
        int r = i >> 9, q = i & 511;
        int b = r / M_, m = r % M_;
        int x = m / 63, j = m % 63;
        int y = j + (j >= x ? 1 : 0);
        const float4* e4 = (const float4*)enc;
        float4 v = (q < 256) ? e4[(b * 64 + x) * 256 + q]
                             : e4[(b * 64 + y) * 256 + (q - 256)];
        ((float4*)out0)[i] = v;
    } else if (bx < 64638) {                // coords: BM rows
        int r = (bx - 64512) * 256 + threadIdx.x;
        int b = r / M_, m = r % M_;
        int x = m / 63, j = m % 63;
        int y = j + (j >= x ? 1 : 0);
        const float4* c4 = (const float4*)coords;
        ((float4*)out1)[r] = c4[b * 64 + x];
        ((float4*)out2)[r] = c4[b * 64 + y];
    } else {                                // prior: BM*117 floats
        int i = (bx - 64638) * 256 + threadIdx.x;
        int r = i / NCLS, c = i % NCLS;
        int b = r / M_, m = r % M_;
        int x = m / 63, j = m % 63;
        int y = j + (j >= x ? 1 : 0);
        int lab = labels[b * 64 + y];
        float val = 0.f;
        if (c == lab) {
            float w = b3[0] + wpart[r];
            float A = 1.f / (1.f + expf(-w));
            float sx = scores[b * 64 + x], sy = scores[b * 64 + y];
            val = A * lis_f(sx) * lis_f(sy);
        }
        out3[i] = val;
    }
}

// ---------------------------------------------------------------------------
extern "C" void kernel_launch(void* const* d_in, const int* in_sizes, int n_in,
                              void* d_out, int out_size, void* d_ws, size_t ws_size,
                              hipStream_t stream)
{
    const float* box_features = (const float*)d_in[0];
    const float* box_coords   = (const float*)d_in[1];
    const int*   box_labels   = (const int*)d_in[2];
    const float* box_scores   = (const float*)d_in[3];
    const float* W1  = (const float*)d_in[4];
    const float* b1  = (const float*)d_in[5];
    const float* W2  = (const float*)d_in[6];
    const float* b2  = (const float*)d_in[7];
    const float* W3  = (const float*)d_in[8];
    const float* b3  = (const float*)d_in[9];
    const float* Ws  = (const float*)d_in[10];
    const float* bs  = (const float*)d_in[11];
    const float* Wo  = (const float*)d_in[12];
    const float* bo  = (const float*)d_in[13];
    const float* Wsu = (const float*)d_in[14];
    const float* Wou = (const float*)d_in[15];

    float* wsf  = (float*)d_ws;
    float* encA = wsf;           wsf += (size_t)B_ * N_ * R_;    // fp32 final enc
    float* wpart= wsf;           wsf += (size_t)BM;
    float* biasFull = wsf;       wsf += 3072;

    unsigned short* wsu = (unsigned short*)wsf;
    unsigned short* enc0bf = wsu;  wsu += (size_t)B_ * N_ * R_;     // 2M
    unsigned short* encIbf = wsu;  wsu += (size_t)B_ * N_ * R_;     // 2M
    unsigned short* XX     = wsu;  wsu += (size_t)B_ * N_ * 3072;   // 6.3M
    unsigned short* msghbf = wsu;  wsu += (size_t)B_ * NH * REP;    // 0.5M
    unsigned short* enchbf = wsu;  wsu += (size_t)B_ * NH * R_;     // 0.5M
    unsigned short* Gsbf   = wsu;  wsu += (size_t)B_ * NH * REP;    // 0.5M
    unsigned short* Wfused = wsu;  wsu += (size_t)3072 * 1024;
    unsigned short* W2t    = wsu;  wsu += (size_t)512 * 1024;
    unsigned short* Wst    = wsu;  wsu += (size_t)1024 * 1024;
    unsigned short* Wsut   = wsu;  wsu += (size_t)1024 * 2048;
    unsigned short* Wout   = wsu;  wsu += (size_t)1024 * 2048;

    float* out0 = (float*)d_out;                       // pair [32256, 2048]
    float* out1 = out0 + (size_t)BM * 2048;            // bh   [32,1008,4]
    float* out2 = out1 + (size_t)BM * 4;               // bo   [32,1008,4]
    float* out3 = out2 + (size_t)BM * 4;               // prior[32256, 117]

    // ---- prep (1 dispatch: weights + bias + input convert) ----
    prep_all<<<9740, 256, 0, stream>>>(W1, W2, Wo, Ws, Wsu, Wou, bo, b1, box_features,
                                       Wfused, W2t, Wst, Wsut, Wout, biasFull, enc0bf);

    for (int it = 0; it < 2; ++it) {
        const unsigned short* enc = (it == 0) ? enc0bf : encIbf;
        // XX = enc @ [W1bot | Wo] (all rows) | W1top (human rows only)
        gemm_uvgo<<<288, 256, 0, stream>>>(enc, Wfused, biasFull, XX);
        // one-pass fused pair MLP (8-phase) -> wpart
        pair_bf<<<252, 512, 0, stream>>>(XX, W2t, b2, W3, wpart);
        // msgh = A @ Go  (A recomputed from wpart)
        msgh_kernel<<<256, 128, 0, stream>>>(wpart, b3, XX, msghbf);
        // ench = concat(enc[humans], msgh) @ Wsu
        gemm_small<<<128, 256, 0, stream>>>(enc, msghbf, Wsut, nullptr,
                                            enchbf, 2048, 1024, 0, MD_CC1);
        // Gs = relu(ench @ Ws + bs)
        gemm_small<<<128, 256, 0, stream>>>(enchbf, nullptr, Wst, bs,
                                            Gsbf, 1024, 1024, 1, MD_DIRECT);
        // encOut = enc_upd @ Wou_top + A^T @ (Gs @ Wou_bot)   (fused, K=1024)
        gemm_cc2<<<512, 256, 0, stream>>>(enc, enchbf, Gsbf, Wout, wpart, b3,
                                          (it == 1) ? encA : nullptr,
                                          (it == 0) ? encIbf : nullptr);
    }

    // fused tail outputs (pair gather + coords + prior) — 1 dispatch
    outputs_all<<<79380, 256, 0, stream>>>(encA, box_coords, wpart, b3,
                                           box_labels, box_scores,
                                           out0, out1, out2, out3);
}